// Round 1
// baseline (550.826 us; speedup 1.0000x reference)
//
#include <hip/hip_runtime.h>
#include <cstddef>

#define Hdim 1024
#define Bdim 64
#define Idim 128

// BETA = 10.0 / 0.192
#define BETA_F 52.083333333333336f
#define INV_BETA_F 0.0192f
#define LN2_F 0.6931471805599453f

__device__ __forceinline__ float sigf(float x) {
    return 1.0f / (1.0f + __expf(-x));
}

// log(cosh(t)) = |t| + log1p(exp(-2|t|)) - ln2   (stable, matches fp32 ref)
__device__ __forceinline__ float logcoshf_(float t) {
    float a = fabsf(t);
    return a + log1pf(__expf(-2.0f * a)) - LN2_F;
}

// ---------------------------------------------------------------------------
// Pre-kernel: rates r = sigmoid(v_t)  (flat B*H),
// and x-projections: membx[j,b] = p_r@x + b_r ; gatex[j,b] = |p_r|@x + g_z
// grid = H blocks of B threads.
// ---------------------------------------------------------------------------
__global__ void pre_kernel(const float* __restrict__ x,
                           const float* __restrict__ v_t,
                           const float* __restrict__ p_r,
                           const float* __restrict__ b_r,
                           const float* __restrict__ g_z,
                           float* __restrict__ r_ws,
                           float* __restrict__ membx,
                           float* __restrict__ gatex) {
    const int j = blockIdx.x;   // 0..H-1
    const int b = threadIdx.x;  // 0..B-1
    const float* pr = p_r + (size_t)j * Idim;
    float accm = 0.0f, accg = 0.0f;
#pragma unroll 4
    for (int i = 0; i < Idim; ++i) {
        float p  = pr[i];              // wave-uniform -> scalar load
        float xv = x[i * Bdim + b];    // coalesced
        accm = fmaf(p, xv, accm);
        accg = fmaf(fabsf(p), xv, accg);
    }
    membx[j * Bdim + b] = accm + b_r[j];
    gatex[j * Bdim + b] = accg + g_z[j];

    // flat elementwise over B*H (index mapping irrelevant)
    int id = j * Bdim + b;  // 0..65535
    r_ws[id] = sigf(v_t[id]);
}

// ---------------------------------------------------------------------------
// Main kernel: one block per postsynaptic row j. 4 waves x 16 batches each.
// LDS holds per-row transforms computed once, reused across all 64 batches.
// ---------------------------------------------------------------------------
__global__ __launch_bounds__(256, 4) void main_kernel(
    const float* __restrict__ X,
    const float* __restrict__ U,
    const float* __restrict__ raw_w_r,
    const float* __restrict__ c_x,
    const float* __restrict__ c_u,
    const float* __restrict__ c_U,
    const float* __restrict__ v_t,
    const float* __restrict__ a_exc,
    const float* __restrict__ a_inh,
    const float* __restrict__ r_ws,
    const float* __restrict__ membx,
    const float* __restrict__ gatex,
    float* __restrict__ out) {
    __shared__ __align__(16) float s_zx[Hdim];
    __shared__ __align__(16) float s_zu[Hdim];
    __shared__ __align__(16) float s_uc[Hdim];
    __shared__ __align__(16) float s_wr[Hdim];
    __shared__ __align__(16) float s_wa[Hdim];  // w_r * A[k]

    const int j   = blockIdx.x;
    const int tid = threadIdx.x;

    const float Aexc = 10.0f * sigf(a_exc[0]);
    const float Ainh = 10.0f * sigf(a_inh[0]);

    // ---- stage per-row transcendentals into LDS (256 thr x 4 elems) ----
    {
        const int k = tid * 4;
        const size_t ro = (size_t)j * Hdim + k;
        float4 rw = *(const float4*)(raw_w_r + ro);
        float4 cx = *(const float4*)(c_x + ro);
        float4 cu = *(const float4*)(c_u + ro);
        float4 cN = *(const float4*)(c_U + ro);
        const float A = (k < Hdim / 2) ? Aexc : Ainh;  // k..k+3 same half

        float w0 = logcoshf_(BETA_F * rw.x) * INV_BETA_F;
        float w1 = logcoshf_(BETA_F * rw.y) * INV_BETA_F;
        float w2 = logcoshf_(BETA_F * rw.z) * INV_BETA_F;
        float w3 = logcoshf_(BETA_F * rw.w) * INV_BETA_F;
        s_wr[k + 0] = w0; s_wa[k + 0] = w0 * A;
        s_wr[k + 1] = w1; s_wa[k + 1] = w1 * A;
        s_wr[k + 2] = w2; s_wa[k + 2] = w2 * A;
        s_wr[k + 3] = w3; s_wa[k + 3] = w3 * A;

        s_zx[k + 0] = 0.001f + 0.099f * sigf(cx.x);
        s_zx[k + 1] = 0.001f + 0.099f * sigf(cx.y);
        s_zx[k + 2] = 0.001f + 0.099f * sigf(cx.z);
        s_zx[k + 3] = 0.001f + 0.099f * sigf(cx.w);

        s_zu[k + 0] = 0.001f + 0.099f * sigf(cu.x);
        s_zu[k + 1] = 0.001f + 0.099f * sigf(cu.y);
        s_zu[k + 2] = 0.001f + 0.099f * sigf(cu.z);
        s_zu[k + 3] = 0.001f + 0.099f * sigf(cu.w);

        s_uc[k + 0] = 0.9f * sigf(cN.x);
        s_uc[k + 1] = 0.9f * sigf(cN.y);
        s_uc[k + 2] = 0.9f * sigf(cN.z);
        s_uc[k + 3] = 0.9f * sigf(cN.w);
    }
    __syncthreads();

    const int wave = tid >> 6;
    const int lane = tid & 63;

    for (int b = wave; b < Bdim; b += 4) {
        const float* Xb = X + (size_t)b * Hdim * Hdim + (size_t)j * Hdim;
        const float* Ub = U + (size_t)b * Hdim * Hdim + (size_t)j * Hdim;
        const float* rb = r_ws + b * Hdim;
        const float rj = rb[j];  // r[j,b] — the rb broadcast in the reference

        float rec = 0.0f, gate = 0.0f;
#pragma unroll
        for (int it = 0; it < 4; ++it) {
            const int k = (it * 64 + lane) * 4;
            float4 Xv = *(const float4*)(Xb + k);
            float4 Uv = *(const float4*)(Ub + k);
            float4 rv = *(const float4*)(rb + k);
            float4 zx = *(const float4*)(s_zx + k);
            float4 zu = *(const float4*)(s_zu + k);
            float4 uc = *(const float4*)(s_uc + k);
            float4 wr = *(const float4*)(s_wr + k);
            float4 wa = *(const float4*)(s_wa + k);

#define COMPONENT(c)                                                          \
    {                                                                         \
        float xn = zx.c + (1.0f - zx.c) * Xv.c - Uv.c * Xv.c * rj;            \
        float un = uc.c * zu.c + (1.0f - zu.c) * Uv.c +                       \
                   uc.c * (1.0f - Uv.c) * rj;                                 \
        un = fminf(fmaxf(un, uc.c), 1.0f);                                    \
        rec  = fmaf(xn * un * wr.c, rv.c, rec);                               \
        gate = fmaf(wa.c, rv.c, gate);                                        \
    }
            COMPONENT(x)
            COMPONENT(y)
            COMPONENT(z)
            COMPONENT(w)
#undef COMPONENT
        }

        // butterfly reduce across the 64-lane wave
#pragma unroll
        for (int off = 32; off > 0; off >>= 1) {
            rec  += __shfl_xor(rec, off, 64);
            gate += __shfl_xor(gate, off, 64);
        }

        if (lane == 0) {
            float z  = 0.1f * sigf(gate + gatex[j * Bdim + b]);
            float vt = v_t[(size_t)b * Hdim + j];
            float vn = (1.0f - z) * vt + 0.1f * (rec + membx[j * Bdim + b]);
            out[(size_t)b * Hdim + j] = vn;
        }
    }
}

extern "C" void kernel_launch(void* const* d_in, const int* in_sizes, int n_in,
                              void* d_out, int out_size, void* d_ws, size_t ws_size,
                              hipStream_t stream) {
    const float* x       = (const float*)d_in[0];   // (I,B)
    const float* v_t     = (const float*)d_in[1];   // (B,H)
    const float* X       = (const float*)d_in[2];   // (B,H,H)
    const float* U       = (const float*)d_in[3];   // (B,H,H)
    const float* raw_w_r = (const float*)d_in[4];   // (H,H)
    const float* p_r     = (const float*)d_in[5];   // (H,I)
    const float* b_r     = (const float*)d_in[6];   // (H,1)
    const float* g_z     = (const float*)d_in[7];   // (H,1)
    const float* c_x     = (const float*)d_in[8];   // (H,H)
    const float* c_u     = (const float*)d_in[9];   // (H,H)
    const float* c_U     = (const float*)d_in[10];  // (H,H)
    const float* a_exc   = (const float*)d_in[11];  // scalar
    const float* a_inh   = (const float*)d_in[12];  // scalar

    float* out = (float*)d_out;  // (B,H) fp32

    float* r_ws  = (float*)d_ws;              // B*H
    float* membx = r_ws + Bdim * Hdim;        // H*B
    float* gatex = membx + Hdim * Bdim;       // H*B

    pre_kernel<<<dim3(Hdim), dim3(Bdim), 0, stream>>>(
        x, v_t, p_r, b_r, g_z, r_ws, membx, gatex);

    main_kernel<<<dim3(Hdim), dim3(256), 0, stream>>>(
        X, U, raw_w_r, c_x, c_u, c_U, v_t, a_exc, a_inh,
        r_ws, membx, gatex, out);
}